// Round 15
// baseline (199.338 us; speedup 1.0000x reference)
//
#include <hip/hip_runtime.h>

#define N_NODES 50000
#define N_EDGES 800000
#define IN_DIM  128
#define HID_DIM 128
#define OUT_DIM 64

#define NPAD 50176                          // N_NODES rounded up (multiple of 128)
#define CAP  64                             // fixed CSR slots/node (max deg ~36, Poisson(16))
#define GEMM1B ((N_NODES + 63) / 64)        // 782 gemm1 blocks (64 rows each, 256 thr)
#define FILLB (N_EDGES / 256)               // 3125 fill blocks, exact
#define W2PREPB 8                           // w2t prep blocks (2048 ushort4 exactly)

typedef __attribute__((ext_vector_type(8))) short bf16x8;   // 8 bf16 in 4 VGPRs
typedef __attribute__((ext_vector_type(4))) float f32x4;
typedef __attribute__((ext_vector_type(2))) float f32x2;

// float -> bf16 (round-to-nearest-even), as ushort
__device__ __forceinline__ unsigned short f2bf(float f) {
    unsigned u = __float_as_uint(f);
    u += 0x7fffu + ((u >> 16) & 1u);
    return (unsigned short)(u >> 16);
}
// bf16 pair unpack from a uint (little-endian: low ushort first)
__device__ __forceinline__ float bflo(unsigned u) { return __uint_as_float(u << 16); }
__device__ __forceinline__ float bfhi(unsigned u) { return __uint_as_float(u & 0xffff0000u); }

// accumulate one uint4 (8 bf16) into acc[8]
#define ACC8(u)  do { \
    acc[0] += bflo(u.x); acc[1] += bfhi(u.x); \
    acc[2] += bflo(u.y); acc[3] += bfhi(u.y); \
    acc[4] += bflo(u.z); acc[5] += bfhi(u.z); \
    acc[6] += bflo(u.w); acc[7] += bfhi(u.w); } while (0)

// float -> fp8 (OCP e4m3 on gfx950) single byte, via HW packed convert
__device__ __forceinline__ unsigned char f2fp8(float f) {
    return (unsigned char)(__builtin_amdgcn_cvt_pk_fp8_f32(f, f, 0, false) & 0xff);
}

// accumulate one uint4 of fp8 (16 channels) into acc[16]
#define ACCF16(u)  do { \
    f32x2 p0 = __builtin_amdgcn_cvt_pk_f32_fp8((int)u.x, false); \
    f32x2 p1 = __builtin_amdgcn_cvt_pk_f32_fp8((int)u.x, true);  \
    f32x2 p2 = __builtin_amdgcn_cvt_pk_f32_fp8((int)u.y, false); \
    f32x2 p3 = __builtin_amdgcn_cvt_pk_f32_fp8((int)u.y, true);  \
    f32x2 p4 = __builtin_amdgcn_cvt_pk_f32_fp8((int)u.z, false); \
    f32x2 p5 = __builtin_amdgcn_cvt_pk_f32_fp8((int)u.z, true);  \
    f32x2 p6 = __builtin_amdgcn_cvt_pk_f32_fp8((int)u.w, false); \
    f32x2 p7 = __builtin_amdgcn_cvt_pk_f32_fp8((int)u.w, true);  \
    acc[0]  += p0[0]; acc[1]  += p0[1]; acc[2]  += p1[0]; acc[3]  += p1[1]; \
    acc[4]  += p2[0]; acc[5]  += p2[1]; acc[6]  += p3[0]; acc[7]  += p3[1]; \
    acc[8]  += p4[0]; acc[9]  += p4[1]; acc[10] += p5[0]; acc[11] += p5[1]; \
    acc[12] += p6[0]; acc[13] += p6[1]; acc[14] += p7[0]; acc[15] += p7[1]; } while (0)

// deg -> dinv (reference: deg>0 ? rsqrt(deg) : 0)
__device__ __forceinline__ float deg2dinv(int deg) {
    return (deg > 0) ? rsqrtf((float)deg) : 0.0f;
}

#define W1T_STRIDE 136   // LDS row pad: 272B stride -> 2-way bank alias (free, m136)

// ---------------- dispatch 2: W2^T prep + single-pass atomic CSR fill ----------------
// r7-verified: ~46-54us @ 8 VGPR, atomic-bound, fragile to co-running work (r8).

__global__ __launch_bounds__(256) void prep_fill_kernel(const int* __restrict__ src,
                                                        const int* __restrict__ dst,
                                                        int* __restrict__ cnt,
                                                        unsigned short* __restrict__ csr_src,
                                                        const float* __restrict__ W2,
                                                        unsigned short* __restrict__ w2t) {
    int bid = blockIdx.x;
    int tid = threadIdx.x;
    if (bid < W2PREPB) {
        // W2T[c][k] = bf16(W2[k][c]); 64x128 -> 2048 ushort4 (8 blocks exactly)
        int idx = bid * 256 + tid;
        int c = idx >> 5, k4 = (idx & 31) * 4;
        ushort4 o;
        o.x = f2bf(W2[(k4 + 0) * 64 + c]);
        o.y = f2bf(W2[(k4 + 1) * 64 + c]);
        o.z = f2bf(W2[(k4 + 2) * 64 + c]);
        o.w = f2bf(W2[(k4 + 3) * 64 + c]);
        *(ushort4*)(w2t + c * 128 + k4) = o;
    } else {
        // depth-1 atomic chains: 800k independent atomics (r15 measured win vs depth-4)
        int e = (bid - W2PREPB) * 256 + tid;   // exact: FILLB*256 == N_EDGES
        int s = src[e], d = dst[e];
        int slot = atomicAdd(&cnt[d], 1);
        if (slot < CAP) csr_src[(d << 6) + slot] = (unsigned short)s;
    }
}

// ---------------- dispatch 3: GEMM1 (after fill) -> h1f8 = fp8(dinv_row*(x@W1)) ----
// dinv PRE-SCALED into h1 (r13/r14 verified: removes 800k scattered cnt-gathers
// from agg1). W1^T self-staged in LDS from fp32 W1.

__global__ __launch_bounds__(256) void gemm1_kernel(const float* __restrict__ x,
                                                    const float* __restrict__ W1,
                                                    const int* __restrict__ cnt,
                                                    unsigned char* __restrict__ h1f8) {
    __shared__ unsigned short w1t[128 * W1T_STRIDE];     // [c][k] bf16, padded

    int tid = threadIdx.x;
    // stage W1^T: W1 row-major [k][c]; idx=k*128+c read coalesced, scatter to [c][k]
#pragma unroll
    for (int i = 0; i < 64; ++i) {
        int idx = i * 256 + tid;
        int k = idx >> 7, c = idx & 127;
        w1t[c * W1T_STRIDE + k] = f2bf(W1[idx]);
    }
    __syncthreads();

    int wave = tid >> 6;
    int lane = tid & 63;
    int n = lane & 15, quad = lane >> 4;
    int row0 = blockIdx.x * 64 + wave * 16;

    int arow = row0 + n;
    if (arow >= N_NODES) arow = N_NODES - 1;             // clamp (stores guarded)
    const float* aptr = x + (size_t)arow * 128 + quad * 8;
    const unsigned short* bbase = w1t + (size_t)n * W1T_STRIDE + quad * 8;

    f32x4 acc[8];
#pragma unroll
    for (int t = 0; t < 8; ++t) acc[t] = (f32x4){0.f, 0.f, 0.f, 0.f};

#pragma unroll
    for (int w4 = 0; w4 < 4; ++w4) {
        float4 f0 = *(const float4*)(aptr + w4 * 32);
        float4 f1 = *(const float4*)(aptr + w4 * 32 + 4);
        bf16x8 af;
        af[0] = (short)f2bf(f0.x); af[1] = (short)f2bf(f0.y);
        af[2] = (short)f2bf(f0.z); af[3] = (short)f2bf(f0.w);
        af[4] = (short)f2bf(f1.x); af[5] = (short)f2bf(f1.y);
        af[6] = (short)f2bf(f1.z); af[7] = (short)f2bf(f1.w);
#pragma unroll
        for (int t = 0; t < 8; ++t) {
            bf16x8 bf = *(const bf16x8*)(bbase + (size_t)t * 16 * W1T_STRIDE + w4 * 32);
            acc[t] = __builtin_amdgcn_mfma_f32_16x16x32_bf16(af, bf, acc[t], 0, 0, 0);
        }
    }

#pragma unroll
    for (int r = 0; r < 4; ++r) {
        int row = row0 + quad * 4 + r;
        if (row < N_NODES) {
            float dn = deg2dinv(cnt[row]);
            unsigned char* o = h1f8 + (size_t)row * 128 + n;
#pragma unroll
            for (int t = 0; t < 8; ++t) o[t * 16] = f2fp8(acc[t][r] * dn);
        }
    }
}

// ---------------- dispatch 4: fused agg1 + GEMM2 (wave-per-node gather) ----------
// Gather reshaped to agg2's PROVEN shape: one wave per node, 8 edge-groups x
// 8 uint4-slots (16 fp8 ch/lane) -> 8 distinct 128B rows per load instruction
// (was 4 with the 16-thread/node shape; r14 measured agg1 ~60us vs agg2 ~43us at
// IDENTICAL byte volume -- request shape is the suspected difference).
// Block = 1024 thr = 16 waves = 16 nodes; phase 2 MFMA runs on waves 0-3.

#define A1T_STRIDE 136

__global__ __launch_bounds__(1024) void agg1_gemm2_fused(const unsigned short* __restrict__ csr_src,
                                                         const int* __restrict__ cnt,
                                                         const float* __restrict__ b1,
                                                         const unsigned char* __restrict__ h1f8,
                                                         const unsigned short* __restrict__ w2t,
                                                         unsigned short* __restrict__ h2b) {
    __shared__ unsigned short a1t[16 * A1T_STRIDE];      // 16 x 128 bf16, padded

    int node0 = blockIdx.x * 16;
    int wave = threadIdx.x >> 6;     // node within block (0..15)
    int lane = threadIdx.x & 63;
    int grp = lane >> 3;             // 8 edge groups: edge j = grp + 8t
    int q   = lane & 7;              // uint4 slot (16 fp8 channels each)
    int node = node0 + wave;         // always < N_NODES (3125*16 = 50000 exact)
    int start = node << 6;           // fixed-stride CSR row
    int m = cnt[node];
    float dn = deg2dinv(m);
    if (m > CAP) m = CAP;            // never taken; bounds safety

    float acc[16] = {};
    int j = grp;
    for (; j + 8 < m; j += 16) {
        int s0 = csr_src[start + j];
        int s1 = csr_src[start + j + 8];
        uint4 u0 = ((const uint4*)(h1f8 + (size_t)s0 * 128))[q];
        uint4 u1 = ((const uint4*)(h1f8 + (size_t)s1 * 128))[q];
        ACCF16(u0); ACCF16(u1);
    }
    if (j < m) {
        int s0 = csr_src[start + j];
        uint4 u0 = ((const uint4*)(h1f8 + (size_t)s0 * 128))[q];
        ACCF16(u0);
    }

    // reduce across the 8 edge-groups (lane bits 3..5)
#pragma unroll
    for (int d = 8; d <= 32; d <<= 1) {
#pragma unroll
        for (int c = 0; c < 16; ++c) acc[c] += __shfl_xor(acc[c], d, 64);
    }

    if (grp == 0) {                  // lanes 0..7; q = lane; channels 16q..16q+15
        int c0 = q * 16;
        float4 bA = *(const float4*)(b1 + c0);
        float4 bB = *(const float4*)(b1 + c0 + 4);
        float4 bC = *(const float4*)(b1 + c0 + 8);
        float4 bD = *(const float4*)(b1 + c0 + 12);
        ushort4 oA, oB, oC, oD;
        oA.x = f2bf(fmaxf(acc[0]  * dn + bA.x, 0.f));
        oA.y = f2bf(fmaxf(acc[1]  * dn + bA.y, 0.f));
        oA.z = f2bf(fmaxf(acc[2]  * dn + bA.z, 0.f));
        oA.w = f2bf(fmaxf(acc[3]  * dn + bA.w, 0.f));
        oB.x = f2bf(fmaxf(acc[4]  * dn + bB.x, 0.f));
        oB.y = f2bf(fmaxf(acc[5]  * dn + bB.y, 0.f));
        oB.z = f2bf(fmaxf(acc[6]  * dn + bB.z, 0.f));
        oB.w = f2bf(fmaxf(acc[7]  * dn + bB.w, 0.f));
        oC.x = f2bf(fmaxf(acc[8]  * dn + bC.x, 0.f));
        oC.y = f2bf(fmaxf(acc[9]  * dn + bC.y, 0.f));
        oC.z = f2bf(fmaxf(acc[10] * dn + bC.z, 0.f));
        oC.w = f2bf(fmaxf(acc[11] * dn + bC.w, 0.f));
        oD.x = f2bf(fmaxf(acc[12] * dn + bD.x, 0.f));
        oD.y = f2bf(fmaxf(acc[13] * dn + bD.y, 0.f));
        oD.z = f2bf(fmaxf(acc[14] * dn + bD.z, 0.f));
        oD.w = f2bf(fmaxf(acc[15] * dn + bD.w, 0.f));
        ushort4* o = (ushort4*)(a1t + wave * A1T_STRIDE + c0);
        o[0] = oA; o[1] = oB; o[2] = oC; o[3] = oD;
    }
    __syncthreads();

    // Phase 2 (waves 0..3): MFMA 16 rows x 16 cols per wave; h2b = bf16(dinv*(a1@W2))
    if (wave < 4) {
        int n = lane & 15, quad = lane >> 4;
        const unsigned short* bbase = w2t + (size_t)(wave * 16 + n) * 128 + quad * 8;
        const unsigned short* abase = a1t + (size_t)n * A1T_STRIDE + quad * 8;

        f32x4 c2 = (f32x4){0.f, 0.f, 0.f, 0.f};
#pragma unroll
        for (int w4 = 0; w4 < 4; ++w4) {
            bf16x8 af = *(const bf16x8*)(abase + w4 * 32);
            bf16x8 bf = *(const bf16x8*)(bbase + w4 * 32);
            c2 = __builtin_amdgcn_mfma_f32_16x16x32_bf16(af, bf, c2, 0, 0, 0);
        }

#pragma unroll
        for (int r = 0; r < 4; ++r) {
            int row = node0 + quad * 4 + r;
            float dr = deg2dinv(cnt[row]);
            h2b[(size_t)row * 64 + wave * 16 + n] = f2bf(c2[r] * dr);
        }
    }
}

// ---------------- dispatch 5: agg2 (bf16 h2 gather -- r11-verified kernel) ----------

__global__ __launch_bounds__(256) void agg2_kernel(const unsigned short* __restrict__ csr_src,
                                                   const int* __restrict__ cnt,
                                                   const float* __restrict__ b2,
                                                   const unsigned short* __restrict__ h2b,
                                                   float* __restrict__ out) {
    int node = blockIdx.x * 4 + (threadIdx.x >> 6);
    if (node >= N_NODES) return;
    int lane = threadIdx.x & 63;
    int grp = lane >> 3;         // 8 groups: edge j = grp + 8t
    int q   = lane & 7;          // uint4 slot (channels 8q..8q+7)
    int start = node << 6;       // fixed-stride CSR row
    int m = cnt[node];
    float dn = deg2dinv(m);
    if (m > CAP) m = CAP;

    float acc[8] = {};

    int j = grp;
    for (; j + 8 < m; j += 16) {
        int s0 = csr_src[start + j];
        int s1 = csr_src[start + j + 8];
        uint4 u0 = ((const uint4*)(h2b + (size_t)s0 * 64))[q];
        uint4 u1 = ((const uint4*)(h2b + (size_t)s1 * 64))[q];
        ACC8(u0); ACC8(u1);
    }
    if (j < m) {
        int s0 = csr_src[start + j];
        uint4 u0 = ((const uint4*)(h2b + (size_t)s0 * 64))[q];
        ACC8(u0);
    }

#pragma unroll
    for (int d = 8; d <= 32; d <<= 1) {
#pragma unroll
        for (int c = 0; c < 8; ++c) acc[c] += __shfl_xor(acc[c], d, 64);
    }

    if (lane < 8) {
        float4 bA = ((const float4*)b2)[2 * q];
        float4 bB = ((const float4*)b2)[2 * q + 1];
        float4 rA, rB;
        rA.x = acc[0] * dn + bA.x;
        rA.y = acc[1] * dn + bA.y;
        rA.z = acc[2] * dn + bA.z;
        rA.w = acc[3] * dn + bA.w;
        rB.x = acc[4] * dn + bB.x;
        rB.y = acc[5] * dn + bB.y;
        rB.z = acc[6] * dn + bB.z;
        rB.w = acc[7] * dn + bB.w;
        float4* o = (float4*)(out + (size_t)node * 64);
        o[2 * q] = rA;
        o[2 * q + 1] = rB;
    }
}

// ---------------- launch ----------------

extern "C" void kernel_launch(void* const* d_in, const int* in_sizes, int n_in,
                              void* d_out, int out_size, void* d_ws, size_t ws_size,
                              hipStream_t stream) {
    const float* x  = (const float*)d_in[0];
    const int*   ei = (const int*)d_in[1];       // [2, E]: src = ei[0..E), dst = ei[E..2E)
    const float* W1 = (const float*)d_in[2];
    const float* b1 = (const float*)d_in[3];
    const float* W2 = (const float*)d_in[4];
    const float* b2 = (const float*)d_in[5];
    float* out = (float*)d_out;

    const int* src = ei;
    const int* dst = ei + N_EDGES;

    // workspace layout (8B-aligned regions)
    char* ws = (char*)d_ws;
    int*   cnt       = (int*)ws;                                 // NPAD ints
    unsigned short* csr_src = (unsigned short*)(cnt + NPAD);     // N_NODES*CAP ushort (6.4MB)
    unsigned char* h1f8 = (unsigned char*)(csr_src + (size_t)N_NODES * CAP);  // 6.4MB
    unsigned short* h2b = (unsigned short*)(h1f8 + (size_t)N_NODES * HID_DIM); // 6.4MB bf16
    unsigned short* w2t = h2b + (size_t)N_NODES * OUT_DIM;

    // 1. zero per-node cursors (200KB, ~2us)
    (void)hipMemsetAsync(cnt, 0, NPAD * sizeof(int), stream);

    // 2. W2^T prep + single-pass atomic CSR fill (isolated; r8 showed fusion hurts)
    prep_fill_kernel<<<W2PREPB + FILLB, 256, 0, stream>>>(src, dst, cnt, csr_src,
                                                          W2, w2t);

    // 3. GEMM1 (reads cnt) -> h1f8 = fp8(dinv_row * (x@W1)), pre-scaled
    gemm1_kernel<<<GEMM1B, 256, 0, stream>>>(x, W1, cnt, h1f8);

    // 4. fused: a1 = relu(b1 + dinv_d * sum h1_s); h2 = bf16(dinv*(a1@W2))
    //    (wave-per-node gather: agg2's proven request shape)
    agg1_gemm2_fused<<<N_NODES / 16, 1024, 0, stream>>>(csr_src, cnt, b1, h1f8, w2t, h2b);

    // 5. out = b2 + dinv * gather(h2)
    agg2_kernel<<<(N_NODES + 3) / 4, 256, 0, stream>>>(csr_src, cnt, b2, h2b, out);
}

// Round 16
// 187.591 us; speedup vs baseline: 1.0626x; 1.0626x over previous
//
#include <hip/hip_runtime.h>

#define N_NODES 50000
#define N_EDGES 800000
#define IN_DIM  128
#define HID_DIM 128
#define OUT_DIM 64

#define NPAD 50176                          // N_NODES rounded up (multiple of 128)
#define CAP  64                             // fixed CSR slots/node (max deg ~36, Poisson(16))
#define GEMM1B ((N_NODES + 63) / 64)        // 782 gemm1 blocks (64 rows each, 256 thr)
#define FILLB (N_EDGES / 256)               // 3125 fill blocks, exact
#define W2PREPB 8                           // w2t prep blocks (2048 ushort4 exactly)
#define AGG1B ((N_NODES + 31) / 32)         // 1563 agg1 blocks (32 nodes each)

typedef __attribute__((ext_vector_type(8))) short bf16x8;   // 8 bf16 in 4 VGPRs
typedef __attribute__((ext_vector_type(4))) float f32x4;
typedef __attribute__((ext_vector_type(2))) float f32x2;

// float -> bf16 (round-to-nearest-even), as ushort
__device__ __forceinline__ unsigned short f2bf(float f) {
    unsigned u = __float_as_uint(f);
    u += 0x7fffu + ((u >> 16) & 1u);
    return (unsigned short)(u >> 16);
}
// bf16 pair unpack from a uint (little-endian: low ushort first)
__device__ __forceinline__ float bflo(unsigned u) { return __uint_as_float(u << 16); }
__device__ __forceinline__ float bfhi(unsigned u) { return __uint_as_float(u & 0xffff0000u); }

// accumulate one uint4 (8 bf16) into acc[8]
#define ACC8(u)  do { \
    acc[0] += bflo(u.x); acc[1] += bfhi(u.x); \
    acc[2] += bflo(u.y); acc[3] += bfhi(u.y); \
    acc[4] += bflo(u.z); acc[5] += bfhi(u.z); \
    acc[6] += bflo(u.w); acc[7] += bfhi(u.w); } while (0)

// float -> fp8 (OCP e4m3 on gfx950) single byte, via HW packed convert
__device__ __forceinline__ unsigned char f2fp8(float f) {
    return (unsigned char)(__builtin_amdgcn_cvt_pk_fp8_f32(f, f, 0, false) & 0xff);
}

// accumulate one uint4 of fp8 (16 channels) into acc[16]
#define ACCF16(u)  do { \
    f32x2 p0 = __builtin_amdgcn_cvt_pk_f32_fp8((int)u.x, false); \
    f32x2 p1 = __builtin_amdgcn_cvt_pk_f32_fp8((int)u.x, true);  \
    f32x2 p2 = __builtin_amdgcn_cvt_pk_f32_fp8((int)u.y, false); \
    f32x2 p3 = __builtin_amdgcn_cvt_pk_f32_fp8((int)u.y, true);  \
    f32x2 p4 = __builtin_amdgcn_cvt_pk_f32_fp8((int)u.z, false); \
    f32x2 p5 = __builtin_amdgcn_cvt_pk_f32_fp8((int)u.z, true);  \
    f32x2 p6 = __builtin_amdgcn_cvt_pk_f32_fp8((int)u.w, false); \
    f32x2 p7 = __builtin_amdgcn_cvt_pk_f32_fp8((int)u.w, true);  \
    acc[0]  += p0[0]; acc[1]  += p0[1]; acc[2]  += p1[0]; acc[3]  += p1[1]; \
    acc[4]  += p2[0]; acc[5]  += p2[1]; acc[6]  += p3[0]; acc[7]  += p3[1]; \
    acc[8]  += p4[0]; acc[9]  += p4[1]; acc[10] += p5[0]; acc[11] += p5[1]; \
    acc[12] += p6[0]; acc[13] += p6[1]; acc[14] += p7[0]; acc[15] += p7[1]; } while (0)

// deg -> dinv (reference: deg>0 ? rsqrt(deg) : 0)
__device__ __forceinline__ float deg2dinv(int deg) {
    return (deg > 0) ? rsqrtf((float)deg) : 0.0f;
}

#define W1T_STRIDE 136   // LDS row pad: 272B stride -> 2-way bank alias (free, m136)

// ---------------- dispatch 2: W2^T prep + single-pass atomic CSR fill ----------------
// r7-verified: ~46-54us @ 8 VGPR, atomic-bound, fragile to co-running work (r8).

__global__ __launch_bounds__(256) void prep_fill_kernel(const int* __restrict__ src,
                                                        const int* __restrict__ dst,
                                                        int* __restrict__ cnt,
                                                        unsigned short* __restrict__ csr_src,
                                                        const float* __restrict__ W2,
                                                        unsigned short* __restrict__ w2t) {
    int bid = blockIdx.x;
    int tid = threadIdx.x;
    if (bid < W2PREPB) {
        // W2T[c][k] = bf16(W2[k][c]); 64x128 -> 2048 ushort4 (8 blocks exactly)
        int idx = bid * 256 + tid;
        int c = idx >> 5, k4 = (idx & 31) * 4;
        ushort4 o;
        o.x = f2bf(W2[(k4 + 0) * 64 + c]);
        o.y = f2bf(W2[(k4 + 1) * 64 + c]);
        o.z = f2bf(W2[(k4 + 2) * 64 + c]);
        o.w = f2bf(W2[(k4 + 3) * 64 + c]);
        *(ushort4*)(w2t + c * 128 + k4) = o;
    } else {
        // depth-1 atomic chains: 800k independent atomics (r15 measured win vs depth-4)
        int e = (bid - W2PREPB) * 256 + tid;   // exact: FILLB*256 == N_EDGES
        int s = src[e], d = dst[e];
        int slot = atomicAdd(&cnt[d], 1);
        if (slot < CAP) csr_src[(d << 6) + slot] = (unsigned short)s;
    }
}

// ---------------- dispatch 3: GEMM1 (after fill) -> h1f8 = fp8(dinv_row*(x@W1)) ----
// dinv PRE-SCALED into h1 (r13/r14 verified). W1^T self-staged in LDS from fp32 W1.

__global__ __launch_bounds__(256) void gemm1_kernel(const float* __restrict__ x,
                                                    const float* __restrict__ W1,
                                                    const int* __restrict__ cnt,
                                                    unsigned char* __restrict__ h1f8) {
    __shared__ unsigned short w1t[128 * W1T_STRIDE];     // [c][k] bf16, padded

    int tid = threadIdx.x;
    // stage W1^T: W1 row-major [k][c]; idx=k*128+c read coalesced, scatter to [c][k]
#pragma unroll
    for (int i = 0; i < 64; ++i) {
        int idx = i * 256 + tid;
        int k = idx >> 7, c = idx & 127;
        w1t[c * W1T_STRIDE + k] = f2bf(W1[idx]);
    }
    __syncthreads();

    int wave = tid >> 6;
    int lane = tid & 63;
    int n = lane & 15, quad = lane >> 4;
    int row0 = blockIdx.x * 64 + wave * 16;

    int arow = row0 + n;
    if (arow >= N_NODES) arow = N_NODES - 1;             // clamp (stores guarded)
    const float* aptr = x + (size_t)arow * 128 + quad * 8;
    const unsigned short* bbase = w1t + (size_t)n * W1T_STRIDE + quad * 8;

    f32x4 acc[8];
#pragma unroll
    for (int t = 0; t < 8; ++t) acc[t] = (f32x4){0.f, 0.f, 0.f, 0.f};

#pragma unroll
    for (int w4 = 0; w4 < 4; ++w4) {
        float4 f0 = *(const float4*)(aptr + w4 * 32);
        float4 f1 = *(const float4*)(aptr + w4 * 32 + 4);
        bf16x8 af;
        af[0] = (short)f2bf(f0.x); af[1] = (short)f2bf(f0.y);
        af[2] = (short)f2bf(f0.z); af[3] = (short)f2bf(f0.w);
        af[4] = (short)f2bf(f1.x); af[5] = (short)f2bf(f1.y);
        af[6] = (short)f2bf(f1.z); af[7] = (short)f2bf(f1.w);
#pragma unroll
        for (int t = 0; t < 8; ++t) {
            bf16x8 bf = *(const bf16x8*)(bbase + (size_t)t * 16 * W1T_STRIDE + w4 * 32);
            acc[t] = __builtin_amdgcn_mfma_f32_16x16x32_bf16(af, bf, acc[t], 0, 0, 0);
        }
    }

#pragma unroll
    for (int r = 0; r < 4; ++r) {
        int row = row0 + quad * 4 + r;
        if (row < N_NODES) {
            float dn = deg2dinv(cnt[row]);
            unsigned char* o = h1f8 + (size_t)row * 128 + n;
#pragma unroll
            for (int t = 0; t < 8; ++t) o[t * 16] = f2fp8(acc[t][r] * dn);
        }
    }
}

// ---------------- dispatch 4: fused agg1 + GEMM2 (8 lanes/node, uint4 gathers) ----
// r14 structure (256-thr block, serial per-thread edge loop, NO reduce) with the
// channel partition changed 16x8B -> 8x16B: each wave-load now touches 8 distinct
// 128B rows (agg2's proven shape) instead of 4, halving agg1's load-instruction
// count (200k->100k) at identical bytes. Summation order per channel is UNCHANGED
// (serial j) -> absmax must stay exactly 2.441e-3 (built-in check).
// Block covers 32 nodes; phase 2: 4 waves x 2 row-blocks (all waves busy, unlike r15).

#define A1T_STRIDE 136

__global__ __launch_bounds__(256) void agg1_gemm2_fused(const unsigned short* __restrict__ csr_src,
                                                        const int* __restrict__ cnt,
                                                        const float* __restrict__ b1,
                                                        const unsigned char* __restrict__ h1f8,
                                                        const unsigned short* __restrict__ w2t,
                                                        unsigned short* __restrict__ h2b) {
    __shared__ unsigned short a1t[32 * A1T_STRIDE];      // 32 x 128 bf16, padded

    int node0 = blockIdx.x * 32;
    int g = threadIdx.x >> 3;        // node within block (0..31)
    int q = threadIdx.x & 7;         // uint4 slot (16 fp8 channels each)
    int node = node0 + g;
    int m = 0;
    float dn = 0.f;
    if (node < N_NODES) {            // last block: nodes 49984..50015, 16 valid
        m = cnt[node];
        dn = deg2dinv(m);
        if (m > CAP) m = CAP;        // never taken; bounds safety
    }
    int start = node << 6;           // fixed-stride CSR row

    float acc[16] = {};
    int j = 0;
    for (; j + 3 < m; j += 4) {
        ushort4 sa = *(const ushort4*)(csr_src + start + j);
        uint4 u0 = ((const uint4*)(h1f8 + (size_t)sa.x * 128))[q];
        uint4 u1 = ((const uint4*)(h1f8 + (size_t)sa.y * 128))[q];
        uint4 u2 = ((const uint4*)(h1f8 + (size_t)sa.z * 128))[q];
        uint4 u3 = ((const uint4*)(h1f8 + (size_t)sa.w * 128))[q];
        ACCF16(u0); ACCF16(u1); ACCF16(u2); ACCF16(u3);
    }
    for (; j < m; ++j) {
        int s0 = csr_src[start + j];
        uint4 u0 = ((const uint4*)(h1f8 + (size_t)s0 * 128))[q];
        ACCF16(u0);
    }

    {
        int c0 = q * 16;
        float4 bA = *(const float4*)(b1 + c0);
        float4 bB = *(const float4*)(b1 + c0 + 4);
        float4 bC = *(const float4*)(b1 + c0 + 8);
        float4 bD = *(const float4*)(b1 + c0 + 12);
        ushort4 oA, oB, oC, oD;
        oA.x = f2bf(fmaxf(acc[0]  * dn + bA.x, 0.f));
        oA.y = f2bf(fmaxf(acc[1]  * dn + bA.y, 0.f));
        oA.z = f2bf(fmaxf(acc[2]  * dn + bA.z, 0.f));
        oA.w = f2bf(fmaxf(acc[3]  * dn + bA.w, 0.f));
        oB.x = f2bf(fmaxf(acc[4]  * dn + bB.x, 0.f));
        oB.y = f2bf(fmaxf(acc[5]  * dn + bB.y, 0.f));
        oB.z = f2bf(fmaxf(acc[6]  * dn + bB.z, 0.f));
        oB.w = f2bf(fmaxf(acc[7]  * dn + bB.w, 0.f));
        oC.x = f2bf(fmaxf(acc[8]  * dn + bC.x, 0.f));
        oC.y = f2bf(fmaxf(acc[9]  * dn + bC.y, 0.f));
        oC.z = f2bf(fmaxf(acc[10] * dn + bC.z, 0.f));
        oC.w = f2bf(fmaxf(acc[11] * dn + bC.w, 0.f));
        oD.x = f2bf(fmaxf(acc[12] * dn + bD.x, 0.f));
        oD.y = f2bf(fmaxf(acc[13] * dn + bD.y, 0.f));
        oD.z = f2bf(fmaxf(acc[14] * dn + bD.z, 0.f));
        oD.w = f2bf(fmaxf(acc[15] * dn + bD.w, 0.f));
        ushort4* o = (ushort4*)(a1t + g * A1T_STRIDE + c0);
        o[0] = oA; o[1] = oB; o[2] = oC; o[3] = oD;
    }
    __syncthreads();

    // Phase 2: 4 waves x 2 row-blocks; h2b = bf16(dinv_row * (a1 @ W2))
    int wave = threadIdx.x >> 6;
    int lane = threadIdx.x & 63;
    int n = lane & 15, quad = lane >> 4;
    const unsigned short* bbase = w2t + (size_t)(wave * 16 + n) * 128 + quad * 8;

#pragma unroll
    for (int rb = 0; rb < 2; ++rb) {
        const unsigned short* abase = a1t + (size_t)(rb * 16 + n) * A1T_STRIDE + quad * 8;
        f32x4 c2 = (f32x4){0.f, 0.f, 0.f, 0.f};
#pragma unroll
        for (int w4 = 0; w4 < 4; ++w4) {
            bf16x8 af = *(const bf16x8*)(abase + w4 * 32);
            bf16x8 bf = *(const bf16x8*)(bbase + w4 * 32);
            c2 = __builtin_amdgcn_mfma_f32_16x16x32_bf16(af, bf, c2, 0, 0, 0);
        }
#pragma unroll
        for (int r = 0; r < 4; ++r) {
            int row = node0 + rb * 16 + quad * 4 + r;
            if (row < N_NODES) {
                float dr = deg2dinv(cnt[row]);
                h2b[(size_t)row * 64 + wave * 16 + n] = f2bf(c2[r] * dr);
            }
        }
    }
}

// ---------------- dispatch 5: agg2 (bf16 h2 gather -- r11-verified kernel) ----------

__global__ __launch_bounds__(256) void agg2_kernel(const unsigned short* __restrict__ csr_src,
                                                   const int* __restrict__ cnt,
                                                   const float* __restrict__ b2,
                                                   const unsigned short* __restrict__ h2b,
                                                   float* __restrict__ out) {
    int node = blockIdx.x * 4 + (threadIdx.x >> 6);
    if (node >= N_NODES) return;
    int lane = threadIdx.x & 63;
    int grp = lane >> 3;         // 8 groups: edge j = grp + 8t
    int q   = lane & 7;          // uint4 slot (channels 8q..8q+7)
    int start = node << 6;       // fixed-stride CSR row
    int m = cnt[node];
    float dn = deg2dinv(m);
    if (m > CAP) m = CAP;

    float acc[8] = {};

    int j = grp;
    for (; j + 8 < m; j += 16) {
        int s0 = csr_src[start + j];
        int s1 = csr_src[start + j + 8];
        uint4 u0 = ((const uint4*)(h2b + (size_t)s0 * 64))[q];
        uint4 u1 = ((const uint4*)(h2b + (size_t)s1 * 64))[q];
        ACC8(u0); ACC8(u1);
    }
    if (j < m) {
        int s0 = csr_src[start + j];
        uint4 u0 = ((const uint4*)(h2b + (size_t)s0 * 64))[q];
        ACC8(u0);
    }

#pragma unroll
    for (int d = 8; d <= 32; d <<= 1) {
#pragma unroll
        for (int c = 0; c < 8; ++c) acc[c] += __shfl_xor(acc[c], d, 64);
    }

    if (lane < 8) {
        float4 bA = ((const float4*)b2)[2 * q];
        float4 bB = ((const float4*)b2)[2 * q + 1];
        float4 rA, rB;
        rA.x = acc[0] * dn + bA.x;
        rA.y = acc[1] * dn + bA.y;
        rA.z = acc[2] * dn + bA.z;
        rA.w = acc[3] * dn + bA.w;
        rB.x = acc[4] * dn + bB.x;
        rB.y = acc[5] * dn + bB.y;
        rB.z = acc[6] * dn + bB.z;
        rB.w = acc[7] * dn + bB.w;
        float4* o = (float4*)(out + (size_t)node * 64);
        o[2 * q] = rA;
        o[2 * q + 1] = rB;
    }
}

// ---------------- launch ----------------

extern "C" void kernel_launch(void* const* d_in, const int* in_sizes, int n_in,
                              void* d_out, int out_size, void* d_ws, size_t ws_size,
                              hipStream_t stream) {
    const float* x  = (const float*)d_in[0];
    const int*   ei = (const int*)d_in[1];       // [2, E]: src = ei[0..E), dst = ei[E..2E)
    const float* W1 = (const float*)d_in[2];
    const float* b1 = (const float*)d_in[3];
    const float* W2 = (const float*)d_in[4];
    const float* b2 = (const float*)d_in[5];
    float* out = (float*)d_out;

    const int* src = ei;
    const int* dst = ei + N_EDGES;

    // workspace layout (8B-aligned regions)
    char* ws = (char*)d_ws;
    int*   cnt       = (int*)ws;                                 // NPAD ints
    unsigned short* csr_src = (unsigned short*)(cnt + NPAD);     // N_NODES*CAP ushort (6.4MB)
    unsigned char* h1f8 = (unsigned char*)(csr_src + (size_t)N_NODES * CAP);  // 6.4MB
    unsigned short* h2b = (unsigned short*)(h1f8 + (size_t)N_NODES * HID_DIM); // 6.4MB bf16
    unsigned short* w2t = h2b + (size_t)N_NODES * OUT_DIM;

    // 1. zero per-node cursors (200KB, ~2us)
    (void)hipMemsetAsync(cnt, 0, NPAD * sizeof(int), stream);

    // 2. W2^T prep + single-pass atomic CSR fill (isolated; r8 showed fusion hurts)
    prep_fill_kernel<<<W2PREPB + FILLB, 256, 0, stream>>>(src, dst, cnt, csr_src,
                                                          W2, w2t);

    // 3. GEMM1 (reads cnt) -> h1f8 = fp8(dinv_row * (x@W1)), pre-scaled
    gemm1_kernel<<<GEMM1B, 256, 0, stream>>>(x, W1, cnt, h1f8);

    // 4. fused: a1 = relu(b1 + dinv_d * sum h1_s); h2 = bf16(dinv*(a1@W2))
    //    (8 lanes/node x uint4: 8 rows per wave-load, r14 structure otherwise)
    agg1_gemm2_fused<<<AGG1B, 256, 0, stream>>>(csr_src, cnt, b1, h1f8, w2t, h2b);

    // 5. out = b2 + dinv * gather(h2)
    agg2_kernel<<<(N_NODES + 3) / 4, 256, 0, stream>>>(csr_src, cnt, b2, h2b, out);
}

// Round 17
// 180.001 us; speedup vs baseline: 1.1074x; 1.0422x over previous
//
#include <hip/hip_runtime.h>

#define N_NODES 50000
#define N_EDGES 800000
#define IN_DIM  128
#define HID_DIM 128
#define OUT_DIM 64

#define NPAD 50176                          // N_NODES rounded up (multiple of 128)
#define CAP  64                             // fixed CSR slots/node (max deg ~36, Poisson(16))
#define GEMM1B ((N_NODES + 63) / 64)        // 782 gemm1 blocks (64 rows each, 256 thr)
#define FILLB (N_EDGES / 256)               // 3125 fill blocks, exact
#define W2PREPB 8                           // w2t prep blocks (2048 ushort4 exactly)

typedef __attribute__((ext_vector_type(8))) short bf16x8;   // 8 bf16 in 4 VGPRs
typedef __attribute__((ext_vector_type(4))) float f32x4;
typedef __attribute__((ext_vector_type(2))) float f32x2;

// float -> bf16 (round-to-nearest-even), as ushort
__device__ __forceinline__ unsigned short f2bf(float f) {
    unsigned u = __float_as_uint(f);
    u += 0x7fffu + ((u >> 16) & 1u);
    return (unsigned short)(u >> 16);
}
// bf16 pair unpack from a uint (little-endian: low ushort first)
__device__ __forceinline__ float bflo(unsigned u) { return __uint_as_float(u << 16); }
__device__ __forceinline__ float bfhi(unsigned u) { return __uint_as_float(u & 0xffff0000u); }

// accumulate one uint4 (8 bf16) into acc[8]
#define ACC8(u)  do { \
    acc[0] += bflo(u.x); acc[1] += bfhi(u.x); \
    acc[2] += bflo(u.y); acc[3] += bfhi(u.y); \
    acc[4] += bflo(u.z); acc[5] += bfhi(u.z); \
    acc[6] += bflo(u.w); acc[7] += bfhi(u.w); } while (0)

// float -> fp8 (OCP e4m3 on gfx950) single byte, via HW packed convert
__device__ __forceinline__ unsigned char f2fp8(float f) {
    return (unsigned char)(__builtin_amdgcn_cvt_pk_fp8_f32(f, f, 0, false) & 0xff);
}

// accumulate 8 fp8 (uint2: bytes 0..7 = channels c..c+7) into acc[8], unscaled
#define ACCF8(u)  do { \
    f32x2 p0 = __builtin_amdgcn_cvt_pk_f32_fp8((int)u.x, false); \
    f32x2 p1 = __builtin_amdgcn_cvt_pk_f32_fp8((int)u.x, true);  \
    f32x2 p2 = __builtin_amdgcn_cvt_pk_f32_fp8((int)u.y, false); \
    f32x2 p3 = __builtin_amdgcn_cvt_pk_f32_fp8((int)u.y, true);  \
    acc[0] += p0[0]; acc[1] += p0[1]; \
    acc[2] += p1[0]; acc[3] += p1[1]; \
    acc[4] += p2[0]; acc[5] += p2[1]; \
    acc[6] += p3[0]; acc[7] += p3[1]; } while (0)

// deg -> dinv (reference: deg>0 ? rsqrt(deg) : 0)
__device__ __forceinline__ float deg2dinv(int deg) {
    return (deg > 0) ? rsqrtf((float)deg) : 0.0f;
}

#define W1T_STRIDE 136   // LDS row pad: 272B stride -> 2-way bank alias (free, m136)

// ---------------- dispatch 2: W2^T prep + single-pass atomic CSR fill ----------------
// r7-verified: ~46-54us @ 8 VGPR, atomic-bound, fragile to co-running work (r8).

__global__ __launch_bounds__(256) void prep_fill_kernel(const int* __restrict__ src,
                                                        const int* __restrict__ dst,
                                                        int* __restrict__ cnt,
                                                        unsigned short* __restrict__ csr_src,
                                                        const float* __restrict__ W2,
                                                        unsigned short* __restrict__ w2t) {
    int bid = blockIdx.x;
    int tid = threadIdx.x;
    if (bid < W2PREPB) {
        // W2T[c][k] = bf16(W2[k][c]); 64x128 -> 2048 ushort4 (8 blocks exactly)
        int idx = bid * 256 + tid;
        int c = idx >> 5, k4 = (idx & 31) * 4;
        ushort4 o;
        o.x = f2bf(W2[(k4 + 0) * 64 + c]);
        o.y = f2bf(W2[(k4 + 1) * 64 + c]);
        o.z = f2bf(W2[(k4 + 2) * 64 + c]);
        o.w = f2bf(W2[(k4 + 3) * 64 + c]);
        *(ushort4*)(w2t + c * 128 + k4) = o;
    } else {
        // depth-1 atomic chains: 800k independent atomics (r15 measured win vs depth-4)
        int e = (bid - W2PREPB) * 256 + tid;   // exact: FILLB*256 == N_EDGES
        int s = src[e], d = dst[e];
        int slot = atomicAdd(&cnt[d], 1);
        if (slot < CAP) csr_src[(d << 6) + slot] = (unsigned short)s;
    }
}

// ---------------- dispatch 3: GEMM1 (after fill) -> h1f8 = fp8(dinv_row*(x@W1)) ----
// dinv PRE-SCALED into h1 (r13/r14 verified: removes 800k scattered cnt-gathers
// from agg1). W1^T self-staged in LDS from fp32 W1.

__global__ __launch_bounds__(256) void gemm1_kernel(const float* __restrict__ x,
                                                    const float* __restrict__ W1,
                                                    const int* __restrict__ cnt,
                                                    unsigned char* __restrict__ h1f8) {
    __shared__ unsigned short w1t[128 * W1T_STRIDE];     // [c][k] bf16, padded

    int tid = threadIdx.x;
    // stage W1^T: W1 row-major [k][c]; idx=k*128+c read coalesced, scatter to [c][k]
#pragma unroll
    for (int i = 0; i < 64; ++i) {
        int idx = i * 256 + tid;
        int k = idx >> 7, c = idx & 127;
        w1t[c * W1T_STRIDE + k] = f2bf(W1[idx]);
    }
    __syncthreads();

    int wave = tid >> 6;
    int lane = tid & 63;
    int n = lane & 15, quad = lane >> 4;
    int row0 = blockIdx.x * 64 + wave * 16;

    int arow = row0 + n;
    if (arow >= N_NODES) arow = N_NODES - 1;             // clamp (stores guarded)
    const float* aptr = x + (size_t)arow * 128 + quad * 8;
    const unsigned short* bbase = w1t + (size_t)n * W1T_STRIDE + quad * 8;

    f32x4 acc[8];
#pragma unroll
    for (int t = 0; t < 8; ++t) acc[t] = (f32x4){0.f, 0.f, 0.f, 0.f};

#pragma unroll
    for (int w4 = 0; w4 < 4; ++w4) {
        float4 f0 = *(const float4*)(aptr + w4 * 32);
        float4 f1 = *(const float4*)(aptr + w4 * 32 + 4);
        bf16x8 af;
        af[0] = (short)f2bf(f0.x); af[1] = (short)f2bf(f0.y);
        af[2] = (short)f2bf(f0.z); af[3] = (short)f2bf(f0.w);
        af[4] = (short)f2bf(f1.x); af[5] = (short)f2bf(f1.y);
        af[6] = (short)f2bf(f1.z); af[7] = (short)f2bf(f1.w);
#pragma unroll
        for (int t = 0; t < 8; ++t) {
            bf16x8 bf = *(const bf16x8*)(bbase + (size_t)t * 16 * W1T_STRIDE + w4 * 32);
            acc[t] = __builtin_amdgcn_mfma_f32_16x16x32_bf16(af, bf, acc[t], 0, 0, 0);
        }
    }

#pragma unroll
    for (int r = 0; r < 4; ++r) {
        int row = row0 + quad * 4 + r;
        if (row < N_NODES) {
            float dn = deg2dinv(cnt[row]);
            unsigned char* o = h1f8 + (size_t)row * 128 + n;
#pragma unroll
            for (int t = 0; t < 8; ++t) o[t * 16] = f2fp8(acc[t][r] * dn);
        }
    }
}

// ---------------- dispatch 4: fused agg1 + GEMM2 (r14-verified, BEST at 179.2us) ----
// Pure 128B fp8 row gathers (no per-edge cnt loads). a1 in LDS as bf16; h2 bf16.
// 16 thr/node x uint2; serial per-thread edge loop, no reduce. r15 (wave/node) and
// r16 (8 thr x uint4) both measured SLOWER -- this shape sits on the gather plateau.

#define A1T_STRIDE 136

__global__ __launch_bounds__(256) void agg1_gemm2_fused(const unsigned short* __restrict__ csr_src,
                                                        const int* __restrict__ cnt,
                                                        const float* __restrict__ b1,
                                                        const unsigned char* __restrict__ h1f8,
                                                        const unsigned short* __restrict__ w2t,
                                                        unsigned short* __restrict__ h2b) {
    __shared__ unsigned short a1t[16 * A1T_STRIDE];      // 16 x 128 bf16, padded

    int node0 = blockIdx.x * 16;
    int g = threadIdx.x >> 4;        // node within block
    int q = threadIdx.x & 15;        // uint2 slot (channels 8q..8q+7)
    int node = node0 + g;            // always < N_NODES (50000 = 3125*16)
    int start = node << 6;           // fixed-stride CSR row
    int m = cnt[node];
    float dn = deg2dinv(m);
    if (m > CAP) m = CAP;            // never taken; bounds safety

    float acc[8] = {};
    int j = 0;
    for (; j + 7 < m; j += 8) {
        ushort4 sa = *(const ushort4*)(csr_src + start + j);
        ushort4 sb = *(const ushort4*)(csr_src + start + j + 4);
        uint2 u0 = ((const uint2*)(h1f8 + (size_t)sa.x * 128))[q];
        uint2 u1 = ((const uint2*)(h1f8 + (size_t)sa.y * 128))[q];
        uint2 u2 = ((const uint2*)(h1f8 + (size_t)sa.z * 128))[q];
        uint2 u3 = ((const uint2*)(h1f8 + (size_t)sa.w * 128))[q];
        uint2 u4 = ((const uint2*)(h1f8 + (size_t)sb.x * 128))[q];
        uint2 u5 = ((const uint2*)(h1f8 + (size_t)sb.y * 128))[q];
        uint2 u6 = ((const uint2*)(h1f8 + (size_t)sb.z * 128))[q];
        uint2 u7 = ((const uint2*)(h1f8 + (size_t)sb.w * 128))[q];
        ACCF8(u0); ACCF8(u1); ACCF8(u2); ACCF8(u3);
        ACCF8(u4); ACCF8(u5); ACCF8(u6); ACCF8(u7);
    }
    for (; j + 3 < m; j += 4) {
        ushort4 sa = *(const ushort4*)(csr_src + start + j);
        uint2 u0 = ((const uint2*)(h1f8 + (size_t)sa.x * 128))[q];
        uint2 u1 = ((const uint2*)(h1f8 + (size_t)sa.y * 128))[q];
        uint2 u2 = ((const uint2*)(h1f8 + (size_t)sa.z * 128))[q];
        uint2 u3 = ((const uint2*)(h1f8 + (size_t)sa.w * 128))[q];
        ACCF8(u0); ACCF8(u1); ACCF8(u2); ACCF8(u3);
    }
    for (; j < m; ++j) {
        int s0 = csr_src[start + j];
        uint2 u0 = ((const uint2*)(h1f8 + (size_t)s0 * 128))[q];
        ACCF8(u0);
    }

    {
        float4 bA = ((const float4*)b1)[2 * q];
        float4 bB = ((const float4*)b1)[2 * q + 1];
        ushort4 oA, oB;
        oA.x = f2bf(fmaxf(acc[0] * dn + bA.x, 0.f));
        oA.y = f2bf(fmaxf(acc[1] * dn + bA.y, 0.f));
        oA.z = f2bf(fmaxf(acc[2] * dn + bA.z, 0.f));
        oA.w = f2bf(fmaxf(acc[3] * dn + bA.w, 0.f));
        oB.x = f2bf(fmaxf(acc[4] * dn + bB.x, 0.f));
        oB.y = f2bf(fmaxf(acc[5] * dn + bB.y, 0.f));
        oB.z = f2bf(fmaxf(acc[6] * dn + bB.z, 0.f));
        oB.w = f2bf(fmaxf(acc[7] * dn + bB.w, 0.f));
        ushort4* o = (ushort4*)(a1t + g * A1T_STRIDE + q * 8);
        o[0] = oA;
        o[1] = oB;
    }
    __syncthreads();

    // Phase 2: MFMA 16 rows x 16 cols per wave; h2b = bf16(dinv_row * (a1 @ W2))
    int wave = threadIdx.x >> 6;
    int lane = threadIdx.x & 63;
    int n = lane & 15, quad = lane >> 4;
    const unsigned short* bbase = w2t + (size_t)(wave * 16 + n) * 128 + quad * 8;
    const unsigned short* abase = a1t + (size_t)n * A1T_STRIDE + quad * 8;

    f32x4 c2 = (f32x4){0.f, 0.f, 0.f, 0.f};
#pragma unroll
    for (int w4 = 0; w4 < 4; ++w4) {
        bf16x8 af = *(const bf16x8*)(abase + w4 * 32);
        bf16x8 bf = *(const bf16x8*)(bbase + w4 * 32);
        c2 = __builtin_amdgcn_mfma_f32_16x16x32_bf16(af, bf, c2, 0, 0, 0);
    }

#pragma unroll
    for (int r = 0; r < 4; ++r) {
        int row = node0 + quad * 4 + r;
        float dr = deg2dinv(cnt[row]);
        h2b[(size_t)row * 64 + wave * 16 + n] = f2bf(c2[r] * dr);
    }
}

// ---------------- dispatch 5: agg2 (bf16 h2 gather -- r11-verified kernel) ----------

__global__ __launch_bounds__(256) void agg2_kernel(const unsigned short* __restrict__ csr_src,
                                                   const int* __restrict__ cnt,
                                                   const float* __restrict__ b2,
                                                   const unsigned short* __restrict__ h2b,
                                                   float* __restrict__ out) {
    int node = blockIdx.x * 4 + (threadIdx.x >> 6);
    if (node >= N_NODES) return;
    int lane = threadIdx.x & 63;
    int grp = lane >> 3;         // 8 groups: edge j = grp + 8t
    int q   = lane & 7;          // uint4 slot (channels 8q..8q+7)
    int start = node << 6;       // fixed-stride CSR row
    int m = cnt[node];
    float dn = deg2dinv(m);
    if (m > CAP) m = CAP;

    float acc[8] = {};

    int j = grp;
    for (; j + 8 < m; j += 16) {
        int s0 = csr_src[start + j];
        int s1 = csr_src[start + j + 8];
        uint4 u0 = ((const uint4*)(h2b + (size_t)s0 * 64))[q];
        uint4 u1 = ((const uint4*)(h2b + (size_t)s1 * 64))[q];
        ACC8(u0); ACC8(u1);
    }
    if (j < m) {
        int s0 = csr_src[start + j];
        uint4 u0 = ((const uint4*)(h2b + (size_t)s0 * 64))[q];
        ACC8(u0);
    }

#pragma unroll
    for (int d = 8; d <= 32; d <<= 1) {
#pragma unroll
        for (int c = 0; c < 8; ++c) acc[c] += __shfl_xor(acc[c], d, 64);
    }

    if (lane < 8) {
        float4 bA = ((const float4*)b2)[2 * q];
        float4 bB = ((const float4*)b2)[2 * q + 1];
        float4 rA, rB;
        rA.x = acc[0] * dn + bA.x;
        rA.y = acc[1] * dn + bA.y;
        rA.z = acc[2] * dn + bA.z;
        rA.w = acc[3] * dn + bA.w;
        rB.x = acc[4] * dn + bB.x;
        rB.y = acc[5] * dn + bB.y;
        rB.z = acc[6] * dn + bB.z;
        rB.w = acc[7] * dn + bB.w;
        float4* o = (float4*)(out + (size_t)node * 64);
        o[2 * q] = rA;
        o[2 * q + 1] = rB;
    }
}

// ---------------- launch ----------------

extern "C" void kernel_launch(void* const* d_in, const int* in_sizes, int n_in,
                              void* d_out, int out_size, void* d_ws, size_t ws_size,
                              hipStream_t stream) {
    const float* x  = (const float*)d_in[0];
    const int*   ei = (const int*)d_in[1];       // [2, E]: src = ei[0..E), dst = ei[E..2E)
    const float* W1 = (const float*)d_in[2];
    const float* b1 = (const float*)d_in[3];
    const float* W2 = (const float*)d_in[4];
    const float* b2 = (const float*)d_in[5];
    float* out = (float*)d_out;

    const int* src = ei;
    const int* dst = ei + N_EDGES;

    // workspace layout (8B-aligned regions)
    char* ws = (char*)d_ws;
    int*   cnt       = (int*)ws;                                 // NPAD ints
    unsigned short* csr_src = (unsigned short*)(cnt + NPAD);     // N_NODES*CAP ushort (6.4MB)
    unsigned char* h1f8 = (unsigned char*)(csr_src + (size_t)N_NODES * CAP);  // 6.4MB
    unsigned short* h2b = (unsigned short*)(h1f8 + (size_t)N_NODES * HID_DIM); // 6.4MB bf16
    unsigned short* w2t = h2b + (size_t)N_NODES * OUT_DIM;

    // 1. zero per-node cursors (200KB, ~2us)
    (void)hipMemsetAsync(cnt, 0, NPAD * sizeof(int), stream);

    // 2. W2^T prep + single-pass atomic CSR fill (isolated; r8 showed fusion hurts)
    prep_fill_kernel<<<W2PREPB + FILLB, 256, 0, stream>>>(src, dst, cnt, csr_src,
                                                          W2, w2t);

    // 3. GEMM1 (reads cnt) -> h1f8 = fp8(dinv_row * (x@W1)), pre-scaled
    gemm1_kernel<<<GEMM1B, 256, 0, stream>>>(x, W1, cnt, h1f8);

    // 4. fused: a1 = relu(b1 + dinv_d * sum h1_s); h2 = bf16(dinv*(a1@W2))
    agg1_gemm2_fused<<<N_NODES / 16, 256, 0, stream>>>(csr_src, cnt, b1, h1f8, w2t, h2b);

    // 5. out = b2 + dinv * gather(h2)
    agg2_kernel<<<(N_NODES + 3) / 4, 256, 0, stream>>>(csr_src, cnt, b2, h2b, out);
}